// Round 1
// baseline (75.701 us; speedup 1.0000x reference)
//
#include <hip/hip_runtime.h>
#include <math.h>

#define BB 32
#define TT 200
#define NCC 10
#define FF 2048
#define KK 3

// ---------------------------------------------------------------------------
// Kernel 1: per-row masked top-3 (jax.lax.top_k semantics: descending values,
// ties -> lower index). One thread per (side, b) row; 64 threads total.
// ---------------------------------------------------------------------------
__global__ void topk_kernel(const float* __restrict__ abnr_magn,
                            const float* __restrict__ norm_magn,
                            const float* __restrict__ abnr_u,
                            const float* __restrict__ norm_u,
                            int* __restrict__ idx_out /* [2][BB][KK] */) {
    int j = blockIdx.x * blockDim.x + threadIdx.x;
    if (j >= 2 * BB) return;
    int side = j / BB;
    int b = j % BB;
    const float* magn = (side == 0) ? abnr_magn : norm_magn;
    const float* u    = (side == 0) ? abnr_u    : norm_u;
    const float scale = 1.0f / (1.0f - 0.7f);  // match ref mask arithmetic

    int chosen[KK];
    for (int k = 0; k < KK; ++k) {
        float best = -INFINITY;
        int bi = 0;
        for (int t = 0; t < TT; ++t) {
            bool excl = false;
            for (int kk = 0; kk < k; ++kk) excl = excl || (chosen[kk] == t);
            if (excl) continue;
            float m = (u[b * TT + t] >= 0.7f) ? scale : 0.0f;
            float v = magn[b * TT + t] * m;
            if (v > best) { best = v; bi = t; }  // strict > keeps lowest index on ties
        }
        chosen[k] = bi;
        idx_out[(side * BB + b) * KK + k] = bi;
    }
}

// ---------------------------------------------------------------------------
// Kernel 2: per (side, nc, b): gather 3 rows of F=2048, mean over K, sum of
// squares over F, sqrt -> l2[side][nc*BB+b]. 640 blocks x 256 threads.
// ---------------------------------------------------------------------------
__global__ void norm_kernel(const float* __restrict__ abnr_feats,
                            const float* __restrict__ norm_feats,
                            const int* __restrict__ idx /* [2][BB][KK] */,
                            float* __restrict__ l2 /* [2][NCC*BB] */) {
    int blk = blockIdx.x;                 // side*NCC*BB + nc*BB + b
    int side = blk / (NCC * BB);
    int r = blk % (NCC * BB);
    int nc = r / BB;
    int b = r % BB;
    const float* feats = (side == 0) ? abnr_feats : norm_feats;
    const int* id = &idx[(side * BB + b) * KK];

    long base = ((long)(nc * BB + b)) * TT * FF;
    const float* p0 = feats + base + (long)id[0] * FF;
    const float* p1 = feats + base + (long)id[1] * FF;
    const float* p2 = feats + base + (long)id[2] * FF;

    float acc = 0.0f;
    for (int f = threadIdx.x; f < FF; f += blockDim.x) {
        float m = (p0[f] + p1[f] + p2[f]) / 3.0f;
        acc += m * m;
    }

    __shared__ float red[256];
    red[threadIdx.x] = acc;
    __syncthreads();
    for (int s = 128; s > 0; s >>= 1) {
        if ((int)threadIdx.x < s) red[threadIdx.x] += red[threadIdx.x + s];
        __syncthreads();
    }
    if (threadIdx.x == 0) l2[blk] = sqrtf(red[0]);
}

// ---------------------------------------------------------------------------
// Kernel 3: final scalar losses. Single block of 64 threads.
// ---------------------------------------------------------------------------
__global__ void final_kernel(const float* __restrict__ l2 /* [2][NCC*BB] */,
                             const float* __restrict__ abnr_sls,
                             const float* __restrict__ norm_sls,
                             const int* __restrict__ idx /* [2][BB][KK] */,
                             float* __restrict__ out) {
    __shared__ float red[64];
    int tid = threadIdx.x;
    const float* l2a = l2;
    const float* l2n = l2 + NCC * BB;

    // loss_rtfm = mean over 320 of (|100 - l2a| + l2n)^2
    float s = 0.0f;
    for (int i = tid; i < NCC * BB; i += 64) {
        float la = fabsf(100.0f - l2a[i]);
        float t = la + l2n[i];
        s += t * t;
    }
    red[tid] = s;
    __syncthreads();
    for (int st = 32; st > 0; st >>= 1) {
        if (tid < st) red[tid] += red[tid + st];
        __syncthreads();
    }
    float loss_rtfm = red[0] / (float)(NCC * BB);
    __syncthreads();

    // BCE terms: per-b mean of 3 gathered scores, clamped log.
    float contrib = 0.0f;
    if (tid < BB) {
        const int* ia = &idx[tid * KK];
        const int* in_ = &idx[(BB + tid) * KK];
        float va = (abnr_sls[tid * TT + ia[0]] + abnr_sls[tid * TT + ia[1]] +
                    abnr_sls[tid * TT + ia[2]]) / 3.0f;
        float vn = (norm_sls[tid * TT + in_[0]] + norm_sls[tid * TT + in_[1]] +
                    norm_sls[tid * TT + in_[2]]) / 3.0f;
        float la = fmaxf(logf(va), -100.0f);
        float ln = fmaxf(logf(1.0f - vn), -100.0f);
        contrib = la + ln;
    }
    red[tid] = contrib;
    __syncthreads();
    for (int st = 32; st > 0; st >>= 1) {
        if (tid < st) red[tid] += red[tid + st];
        __syncthreads();
    }
    if (tid == 0) {
        out[0] = 1e-4f * loss_rtfm;
        out[1] = -red[0] / (float)BB;  // loss_bcea + loss_bcen
    }
}

extern "C" void kernel_launch(void* const* d_in, const int* in_sizes, int n_in,
                              void* d_out, int out_size, void* d_ws, size_t ws_size,
                              hipStream_t stream) {
    const float* abnr_magn  = (const float*)d_in[0];
    const float* norm_magn  = (const float*)d_in[1];
    const float* abnr_feats = (const float*)d_in[2];
    const float* norm_feats = (const float*)d_in[3];
    const float* abnr_sls   = (const float*)d_in[4];
    const float* norm_sls   = (const float*)d_in[5];
    const float* abnr_u     = (const float*)d_in[6];
    const float* norm_u     = (const float*)d_in[7];
    float* out = (float*)d_out;

    int*   idx_ws = (int*)d_ws;                          // 2*32*3 ints
    float* l2_ws  = (float*)((char*)d_ws + 1024);        // 2*10*32 floats

    topk_kernel<<<1, 64, 0, stream>>>(abnr_magn, norm_magn, abnr_u, norm_u, idx_ws);
    norm_kernel<<<2 * NCC * BB, 256, 0, stream>>>(abnr_feats, norm_feats, idx_ws, l2_ws);
    final_kernel<<<1, 64, 0, stream>>>(l2_ws, abnr_sls, norm_sls, idx_ws, out);
}

// Round 2
// 12.706 us; speedup vs baseline: 5.9581x; 5.9581x over previous
//
#include <hip/hip_runtime.h>
#include <math.h>

#define BB 32
#define TT 200
#define NCC 10
#define FF 2048
#define KK 3

// Butterfly argmax across a 64-lane wave: max value, ties -> lower index.
__device__ inline void wave_argmax(float& v, int& i) {
    #pragma unroll
    for (int m = 1; m < 64; m <<= 1) {
        float ov = __shfl_xor(v, m);
        int   oi = __shfl_xor(i, m);
        if (ov > v || (ov == v && oi < i)) { v = ov; i = oi; }
    }
}

// ---------------------------------------------------------------------------
// Fused kernel: one block per (nc, b). Waves 0/1 compute masked top-3 indices
// for (abnr, norm) rows of b; all 256 threads then gather 3+3 rows of F=2048,
// mean over K, L2 over F for both sides, and emit the per-(nc,b) RTFM term.
// nc==0 blocks also emit the per-b BCE contribution.
// ---------------------------------------------------------------------------
__global__ __launch_bounds__(256) void fused_kernel(
        const float* __restrict__ abnr_magn,
        const float* __restrict__ norm_magn,
        const float* __restrict__ abnr_feats,
        const float* __restrict__ norm_feats,
        const float* __restrict__ abnr_sls,
        const float* __restrict__ norm_sls,
        const float* __restrict__ abnr_u,
        const float* __restrict__ norm_u,
        float* __restrict__ partial /* [NCC*BB] */,
        float* __restrict__ bce     /* [BB]     */) {
    const int blk = blockIdx.x;        // nc*BB + b
    const int nc  = blk / BB;
    const int b   = blk % BB;
    const int tid = threadIdx.x;
    const int wave = tid >> 6;
    const int lane = tid & 63;

    __shared__ int   s_idx[2][KK];
    __shared__ float r0[256], r1[256];

    // ---- top-3 (waves 0 and 1; side = wave) ----
    if (wave < 2) {
        const float* magn = (wave == 0) ? abnr_magn : norm_magn;
        const float* u    = (wave == 0) ? abnr_u    : norm_u;
        const float scale = 1.0f / (1.0f - 0.7f);
        float vv[4];
        int   tt[4];
        #pragma unroll
        for (int j = 0; j < 4; ++j) {
            int t = lane + 64 * j;
            if (t < TT) {
                float m = (u[b * TT + t] >= 0.7f) ? scale : 0.0f;
                vv[j] = magn[b * TT + t] * m;
                tt[j] = t;
            } else {
                vv[j] = -INFINITY;
                tt[j] = 1 << 30;
            }
        }
        #pragma unroll
        for (int k = 0; k < KK; ++k) {
            float bv = -INFINITY;
            int   bi = 1 << 30;
            #pragma unroll
            for (int j = 0; j < 4; ++j)
                if (vv[j] > bv || (vv[j] == bv && tt[j] < bi)) { bv = vv[j]; bi = tt[j]; }
            wave_argmax(bv, bi);
            if (lane == 0) s_idx[wave][k] = bi;
            #pragma unroll
            for (int j = 0; j < 4; ++j)
                if (tt[j] == bi) vv[j] = -INFINITY;
        }
    }
    __syncthreads();

    // ---- gather 3 rows per side, mean over K, sum of squares ----
    const size_t base = (size_t)(nc * BB + b) * TT * FF;
    const float* A0 = abnr_feats + base + (size_t)s_idx[0][0] * FF;
    const float* A1 = abnr_feats + base + (size_t)s_idx[0][1] * FF;
    const float* A2 = abnr_feats + base + (size_t)s_idx[0][2] * FF;
    const float* N0 = norm_feats + base + (size_t)s_idx[1][0] * FF;
    const float* N1 = norm_feats + base + (size_t)s_idx[1][1] * FF;
    const float* N2 = norm_feats + base + (size_t)s_idx[1][2] * FF;

    float acc0 = 0.0f, acc1 = 0.0f;
    const float third = 1.0f / 3.0f;
    #pragma unroll
    for (int it = 0; it < 2; ++it) {
        int f = it * 1024 + tid * 4;
        float4 a0 = *(const float4*)(A0 + f);
        float4 a1 = *(const float4*)(A1 + f);
        float4 a2 = *(const float4*)(A2 + f);
        float4 n0 = *(const float4*)(N0 + f);
        float4 n1 = *(const float4*)(N1 + f);
        float4 n2 = *(const float4*)(N2 + f);
        float m;
        m = (a0.x + a1.x + a2.x) * third; acc0 += m * m;
        m = (a0.y + a1.y + a2.y) * third; acc0 += m * m;
        m = (a0.z + a1.z + a2.z) * third; acc0 += m * m;
        m = (a0.w + a1.w + a2.w) * third; acc0 += m * m;
        m = (n0.x + n1.x + n2.x) * third; acc1 += m * m;
        m = (n0.y + n1.y + n2.y) * third; acc1 += m * m;
        m = (n0.z + n1.z + n2.z) * third; acc1 += m * m;
        m = (n0.w + n1.w + n2.w) * third; acc1 += m * m;
    }

    r0[tid] = acc0;
    r1[tid] = acc1;
    __syncthreads();
    for (int s = 128; s > 0; s >>= 1) {
        if (tid < s) { r0[tid] += r0[tid + s]; r1[tid] += r1[tid + s]; }
        __syncthreads();
    }

    if (tid == 0) {
        float l2a = sqrtf(r0[0]);
        float l2n = sqrtf(r1[0]);
        float t = fabsf(100.0f - l2a) + l2n;
        partial[blk] = t * t;
    }

    // ---- BCE contribution, once per b ----
    if (nc == 0 && tid == 64) {  // a wave-1 lane; s_idx valid after the barrier
        float va = (abnr_sls[b * TT + s_idx[0][0]] + abnr_sls[b * TT + s_idx[0][1]] +
                    abnr_sls[b * TT + s_idx[0][2]]) * (1.0f / 3.0f);
        float vn = (norm_sls[b * TT + s_idx[1][0]] + norm_sls[b * TT + s_idx[1][1]] +
                    norm_sls[b * TT + s_idx[1][2]]) * (1.0f / 3.0f);
        float la = fmaxf(logf(va), -100.0f);
        float ln = fmaxf(logf(1.0f - vn), -100.0f);
        bce[b] = la + ln;
    }
}

// ---------------------------------------------------------------------------
// Final: reduce 320 RTFM partials + 32 BCE terms -> the two output scalars.
// ---------------------------------------------------------------------------
__global__ __launch_bounds__(256) void final_kernel(
        const float* __restrict__ partial, const float* __restrict__ bce,
        float* __restrict__ out) {
    __shared__ float red[256];
    int tid = threadIdx.x;

    float s = 0.0f;
    for (int i = tid; i < NCC * BB; i += 256) s += partial[i];
    red[tid] = s;
    __syncthreads();
    for (int st = 128; st > 0; st >>= 1) {
        if (tid < st) red[tid] += red[tid + st];
        __syncthreads();
    }
    float loss_rtfm = red[0] * (1.0f / (NCC * BB));
    __syncthreads();

    red[tid] = (tid < BB) ? bce[tid] : 0.0f;
    __syncthreads();
    for (int st = 128; st > 0; st >>= 1) {
        if (tid < st) red[tid] += red[tid + st];
        __syncthreads();
    }
    if (tid == 0) {
        out[0] = 1e-4f * loss_rtfm;
        out[1] = -red[0] * (1.0f / BB);
    }
}

extern "C" void kernel_launch(void* const* d_in, const int* in_sizes, int n_in,
                              void* d_out, int out_size, void* d_ws, size_t ws_size,
                              hipStream_t stream) {
    const float* abnr_magn  = (const float*)d_in[0];
    const float* norm_magn  = (const float*)d_in[1];
    const float* abnr_feats = (const float*)d_in[2];
    const float* norm_feats = (const float*)d_in[3];
    const float* abnr_sls   = (const float*)d_in[4];
    const float* norm_sls   = (const float*)d_in[5];
    const float* abnr_u     = (const float*)d_in[6];
    const float* norm_u     = (const float*)d_in[7];
    float* out = (float*)d_out;

    float* partial = (float*)d_ws;                       // 320 floats
    float* bce     = (float*)((char*)d_ws + 2048);       // 32 floats

    fused_kernel<<<NCC * BB, 256, 0, stream>>>(abnr_magn, norm_magn,
                                               abnr_feats, norm_feats,
                                               abnr_sls, norm_sls,
                                               abnr_u, norm_u,
                                               partial, bce);
    final_kernel<<<1, 256, 0, stream>>>(partial, bce, out);
}